// Round 1
// baseline (456.343 us; speedup 1.0000x reference)
//
#include <hip/hip_runtime.h>

#define N_NODES 50000
#define N_EDGES 800000
#define NBUCK 196                   // buckets of 256 nodes: bucket = dst >> 8
#define EPB 4096                    // edges per stripe-block in pass A (halved: shorter straggler)
#define NSTRIPE ((N_EDGES + EPB - 1) / EPB)  // 196

typedef __attribute__((ext_vector_type(8))) short short8;
typedef __attribute__((ext_vector_type(4))) float float4v;

__device__ inline unsigned short f2bf(float f) {
    unsigned u = __float_as_uint(f);
    unsigned r = u + 0x7fff + ((u >> 16) & 1);
    return (unsigned short)(r >> 16);
}
__device__ inline float bf2f(unsigned short h) {
    return __uint_as_float(((unsigned)h) << 16);
}

// ---------------- fused: bucket histogram (196 blocks) + weight split (288) ----------

__global__ void __launch_bounds__(256) fused_hist_prep(
    const int* __restrict__ dst, int* __restrict__ bcnt, const float* __restrict__ fcW,
    const float* __restrict__ W, const float* __restrict__ Wl, unsigned short* __restrict__ hi,
    unsigned short* __restrict__ lo) {
    int bx = blockIdx.x;
    if (bx < NSTRIPE) {
        __shared__ int lhist[256];
        int t = threadIdx.x;
        lhist[t] = 0;
        __syncthreads();
        int base = bx * EPB + t;
#pragma unroll 4
        for (int k = 0; k < EPB / 256; k++) {
            int i = base + k * 256;
            if (i < N_EDGES) atomicAdd(&lhist[((unsigned)dst[i]) >> 8], 1);
        }
        __syncthreads();
        if (t < NBUCK) atomicAdd(&bcnt[t], lhist[t]);
    } else {
        // weight split: [0,16384) fcW | [16384,65536) W | [65536,73728) W_last
        int i = (bx - NSTRIPE) * 256 + threadIdx.x;
        float v;
        if (i < 16384) v = fcW[i];
        else if (i < 65536) v = W[i - 16384];
        else if (i < 73728) v = Wl[i - 65536];
        else return;
        unsigned short h = f2bf(v);
        hi[i] = h;
        lo[i] = f2bf(v - bf2f(h));
    }
}

// ---------------- bucket offsets (1 block) ----------------

__global__ void bucket_scan(const int* __restrict__ bcnt, int* __restrict__ boff,
                            int* __restrict__ cursor, int* __restrict__ row_ptr) {
    __shared__ int sm[256];
    int t = threadIdx.x;
    int v = (t < NBUCK) ? bcnt[t] : 0;
    sm[t] = v;
    __syncthreads();
    for (int o = 1; o < 256; o <<= 1) {
        int x = sm[t];
        int a = (t >= o) ? sm[t - o] : 0;
        __syncthreads();
        sm[t] = x + a;
        __syncthreads();
    }
    if (t < NBUCK) {
        boff[t] = sm[t] - v;
        cursor[t] = sm[t] - v;
    }
    if (t == NBUCK - 1) {
        boff[NBUCK] = sm[t];
        row_ptr[N_NODES] = sm[t];
    }
}

// ---------------- split-bf16 MFMA GEMM body (global A) ----------------
// D = Ahi*Whi + Alo*Whi + Ahi*Wlo (missing Alo*Wlo ~ 2^-18 rel).

template <int COLS, bool RELU, bool WRITE_BF, bool BIAS>
__device__ __forceinline__ void gemm_body(int bx, const float* __restrict__ U,
                                          const unsigned short* __restrict__ Whi,
                                          const unsigned short* __restrict__ Wlo,
                                          const float* __restrict__ bias, float* __restrict__ out,
                                          unsigned short* __restrict__ outbf, int nrows) {
    int wave = threadIdx.x >> 6;
    int lane = threadIdx.x & 63;
    int m = lane & 15;
    int quad = lane >> 4;
    int r0 = bx * 64 + wave * 16;
    int rowA = r0 + m;
    if (rowA >= nrows) rowA = nrows - 1;  // clamp OOB loads (stores guarded)

    short8 ahi[4], alo[4];
    const float* arow = U + (size_t)rowA * 128 + quad * 8;
#pragma unroll
    for (int kc = 0; kc < 4; kc++) {
        float4 f0 = *(const float4*)(arow + kc * 32);
        float4 f1 = *(const float4*)(arow + kc * 32 + 4);
        float fv[8] = {f0.x, f0.y, f0.z, f0.w, f1.x, f1.y, f1.z, f1.w};
#pragma unroll
        for (int j = 0; j < 8; j++) {
            unsigned short h = f2bf(fv[j]);
            ahi[kc][j] = (short)h;
            alo[kc][j] = (short)f2bf(fv[j] - bf2f(h));
        }
    }

#pragma unroll
    for (int nt = 0; nt < COLS / 16; nt++) {
        int n = nt * 16 + m;
        const unsigned short* bhp = Whi + (size_t)n * 128 + quad * 8;
        const unsigned short* blp = Wlo + (size_t)n * 128 + quad * 8;
        float4v acc = {0.f, 0.f, 0.f, 0.f};
#pragma unroll
        for (int kc = 0; kc < 4; kc++) {
            short8 bh = *(const short8*)(bhp + kc * 32);
            short8 bl = *(const short8*)(blp + kc * 32);
            acc = __builtin_amdgcn_mfma_f32_16x16x32_bf16(ahi[kc], bh, acc, 0, 0, 0);
            acc = __builtin_amdgcn_mfma_f32_16x16x32_bf16(alo[kc], bh, acc, 0, 0, 0);
            acc = __builtin_amdgcn_mfma_f32_16x16x32_bf16(ahi[kc], bl, acc, 0, 0, 0);
        }
        float bv = 0.f;
        if (BIAS) bv = bias[n];
#pragma unroll
        for (int i = 0; i < 4; i++) {
            int r = r0 + quad * 4 + i;
            if (r < nrows) {
                float v = acc[i] + bv;
                if (RELU) v = fmaxf(v, 0.f);
                out[(size_t)r * COLS + n] = v;
                if (WRITE_BF) outbf[(size_t)r * COLS + n] = f2bf(v);
            }
        }
    }
}

template <int COLS, bool RELU, bool WRITE_BF, bool BIAS>
__global__ void __launch_bounds__(256) gemm_mfma(const float* __restrict__ U,
                                                 const unsigned short* __restrict__ Whi,
                                                 const unsigned short* __restrict__ Wlo,
                                                 const float* __restrict__ bias,
                                                 float* __restrict__ out,
                                                 unsigned short* __restrict__ outbf, int nrows) {
    gemm_body<COLS, RELU, WRITE_BF, BIAS>(blockIdx.x, U, Whi, Wlo, bias, out, outbf, nrows);
}

// ---------------- fused: pass A binning (196 blocks) + SLP GEMM (782) ----------

__global__ void __launch_bounds__(256) fused_binA_gemm(
    const int* __restrict__ src, const int* __restrict__ dst, int* __restrict__ cursor,
    int* __restrict__ packed, const float* __restrict__ X, const unsigned short* __restrict__ whi,
    const unsigned short* __restrict__ wlo, const float* __restrict__ fcb, float* __restrict__ h,
    unsigned short* __restrict__ hbf) {
    int bx = blockIdx.x;
    if (bx < NSTRIPE) {
        __shared__ int lcount[256];
        __shared__ int lbase[256];
        int t = threadIdx.x;
        lcount[t] = 0;
        __syncthreads();
        int base = bx * EPB + t;
#pragma unroll 4
        for (int k = 0; k < EPB / 256; k++) {
            int i = base + k * 256;
            if (i < N_EDGES) atomicAdd(&lcount[((unsigned)dst[i]) >> 8], 1);
        }
        __syncthreads();
        if (t < NBUCK) {
            lbase[t] = atomicAdd(&cursor[t], lcount[t]);
            lcount[t] = 0;
        }
        __syncthreads();
#pragma unroll 4
        for (int k = 0; k < EPB / 256; k++) {
            int i = base + k * 256;
            if (i < N_EDGES) {
                int d = dst[i];
                int wb = ((unsigned)d) >> 8;
                int p = lbase[wb] + atomicAdd(&lcount[wb], 1);
                packed[p] = ((d & 255) << 16) | src[i];
            }
        }
    } else {
        gemm_body<128, true, true, true>(bx - NSTRIPE, X, whi, wlo, fcb, h, hbf, N_NODES);
    }
}

// ---------------- pass B: per-bucket counting sort -> row_ptr + esrc ----------

__global__ void __launch_bounds__(256) binB_kernel(const int* __restrict__ packed,
                                                   const int* __restrict__ boff,
                                                   int* __restrict__ row_ptr,
                                                   int* __restrict__ esrc) {
    __shared__ int sm[256];
    __shared__ int curs[256];
    int b = blockIdx.x;
    int t = threadIdx.x;
    int e0 = boff[b], e1 = boff[b + 1];
    curs[t] = 0;  // use as histogram first
    __syncthreads();
    for (int i = e0 + t; i < e1; i += 256) atomicAdd(&curs[((unsigned)packed[i]) >> 16], 1);
    __syncthreads();
    int v = curs[t];
    sm[t] = v;
    __syncthreads();
    for (int o = 1; o < 256; o <<= 1) {
        int x = sm[t];
        int a = (t >= o) ? sm[t - o] : 0;
        __syncthreads();
        sm[t] = x + a;
        __syncthreads();
    }
    int excl = sm[t] - v;
    curs[t] = excl;
    int node = b * 256 + t;
    if (node < N_NODES) row_ptr[node] = e0 + excl;
    __syncthreads();
    for (int i = e0 + t; i < e1; i += 256) {
        unsigned w = (unsigned)packed[i];
        int p = atomicAdd(&curs[w >> 16], 1);
        esrc[e0 + p] = (int)(w & 0xFFFFu);
    }
}

// ---------------- fused hidden GIN layer: agg -> (LDS) -> GEMM ----------------
// Block = 4 waves = 64 nodes. Phase 1: wave w aggregates nodes w*16..w*16+15
// (bf16 gather payload, fp32 self term from h IN-PLACE), splits u to hi/lo bf16
// and deposits into XOR-swizzled LDS. Phase 2: standard split-bf16 MFMA GEMM with
// A-fragments from LDS. Cross-block dataflow is ONLY via bfin/bfout (ping-pong);
// fp32 h is read/written strictly block-locally (barrier-ordered) -> in-place safe.
// Swizzle: dword index = row*64 + (col_dword ^ ((row&7)<<2)); swz bits (2..4) don't
// overlap the b128's low 2 bits -> 4-dword reads stay contiguous; reader quarter-wave
// lands 2 lanes per 4-dword slot = 2-way = free (m136).

template <bool WRITE_BF>
__global__ void __launch_bounds__(256) fused_agg_gemm(
    float* __restrict__ hio, const unsigned short* __restrict__ bfin,
    const int* __restrict__ row_ptr, const int* __restrict__ esrc,
    const float* __restrict__ eps, int layer, const unsigned short* __restrict__ Whi,
    const unsigned short* __restrict__ Wlo, const float* __restrict__ bias,
    unsigned short* __restrict__ bfout) {
    __shared__ unsigned lds_hi[4096];  // 4 waves * 16 rows * 64 dword feat-pairs
    __shared__ unsigned lds_lo[4096];
    int tid = threadIdx.x;
    int wv = tid >> 6;
    int lane = tid & 63;
    int r0 = blockIdx.x * 64;
    unsigned basew = (unsigned)(wv << 10);
    float ep = 1.0f + eps[layer];
    const unsigned short* hl = bfin + lane * 2;

    // ---- phase 1: aggregate 16 nodes per wave, deposit split-bf16 u into LDS ----
    for (int i = 0; i < 16; i++) {
        int node = r0 + wv * 16 + i;
        if (node >= N_NODES) break;  // uniform per wave; stores below are guarded too
        int beg = __builtin_amdgcn_readfirstlane(row_ptr[node]);
        int end = __builtin_amdgcn_readfirstlane(row_ptr[node + 1]);
        float a0x = 0.f, a0y = 0.f, a1x = 0.f, a1y = 0.f;
        float a2x = 0.f, a2y = 0.f, a3x = 0.f, a3y = 0.f;
        int e = beg;
        for (; e + 3 < end; e += 4) {
            int s0 = esrc[e], s1 = esrc[e + 1], s2 = esrc[e + 2], s3 = esrc[e + 3];
            unsigned v0 = *(const unsigned*)(hl + (size_t)s0 * 128);
            unsigned v1 = *(const unsigned*)(hl + (size_t)s1 * 128);
            unsigned v2 = *(const unsigned*)(hl + (size_t)s2 * 128);
            unsigned v3 = *(const unsigned*)(hl + (size_t)s3 * 128);
            a0x += bf2f((unsigned short)v0); a0y += bf2f((unsigned short)(v0 >> 16));
            a1x += bf2f((unsigned short)v1); a1y += bf2f((unsigned short)(v1 >> 16));
            a2x += bf2f((unsigned short)v2); a2y += bf2f((unsigned short)(v2 >> 16));
            a3x += bf2f((unsigned short)v3); a3y += bf2f((unsigned short)(v3 >> 16));
        }
        for (; e < end; e++) {
            int s = esrc[e];
            unsigned v = *(const unsigned*)(hl + (size_t)s * 128);
            a0x += bf2f((unsigned short)v);
            a0y += bf2f((unsigned short)(v >> 16));
        }
        float sx = (a0x + a1x) + (a2x + a3x);
        float sy = (a0y + a1y) + (a2y + a3y);
        int d = end - beg;
        float inv = (d > 0) ? 1.0f / (float)d : 0.0f;
        float2 hv = *(const float2*)(hio + (size_t)node * 128 + lane * 2);
        float ux = ep * hv.x + sx * inv;
        float uy = ep * hv.y + sy * inv;
        unsigned short u0 = f2bf(ux), u1 = f2bf(uy);
        unsigned hi = (unsigned)u0 | ((unsigned)u1 << 16);
        unsigned lo = (unsigned)f2bf(ux - bf2f(u0)) | ((unsigned)f2bf(uy - bf2f(u1)) << 16);
        unsigned idx = basew + (unsigned)(i * 64) + (unsigned)(lane ^ ((i & 7) << 2));
        lds_hi[idx] = hi;
        lds_lo[idx] = lo;
    }
    __syncthreads();

    // ---- phase 2: MFMA GEMM, A-fragments from swizzled LDS ----
    int m = lane & 15, quad = lane >> 4;
    short8 ahi[4], alo[4];
#pragma unroll
    for (int kc = 0; kc < 4; kc++) {
        unsigned idx =
            basew + (unsigned)(m * 64) + (unsigned)((kc * 16 + quad * 4) ^ ((m & 7) << 2));
        ahi[kc] = *(const short8*)&lds_hi[idx];
        alo[kc] = *(const short8*)&lds_lo[idx];
    }
    int rbase = r0 + wv * 16;
#pragma unroll
    for (int nt = 0; nt < 8; nt++) {
        int n = nt * 16 + m;
        const unsigned short* bhp = Whi + (size_t)n * 128 + quad * 8;
        const unsigned short* blp = Wlo + (size_t)n * 128 + quad * 8;
        float4v acc = {0.f, 0.f, 0.f, 0.f};
#pragma unroll
        for (int kc = 0; kc < 4; kc++) {
            short8 bh = *(const short8*)(bhp + kc * 32);
            short8 bl2 = *(const short8*)(blp + kc * 32);
            acc = __builtin_amdgcn_mfma_f32_16x16x32_bf16(ahi[kc], bh, acc, 0, 0, 0);
            acc = __builtin_amdgcn_mfma_f32_16x16x32_bf16(alo[kc], bh, acc, 0, 0, 0);
            acc = __builtin_amdgcn_mfma_f32_16x16x32_bf16(ahi[kc], bl2, acc, 0, 0, 0);
        }
        float bv = bias[n];
#pragma unroll
        for (int i2 = 0; i2 < 4; i2++) {
            int r = rbase + quad * 4 + i2;
            if (r < N_NODES) {
                float v = fmaxf(acc[i2] + bv, 0.f);
                hio[(size_t)r * 128 + n] = v;
                if (WRITE_BF) bfout[(size_t)r * 128 + n] = f2bf(v);
            }
        }
    }
}

// ---------------- last layer, commuted: out = (1+eps3)*g + mean(g) + b ----------------
// g = h @ Wl^T (64-wide) -> gather volume halved vs aggregating 128-wide h.
// One wave per node; half-wave per edge (lanes 0-31 even edges, 32-63 odd), dword
// bf16-pair gathers, cross-half combine via shfl_xor(32).

__global__ void __launch_bounds__(256) agg64_out(
    const float* __restrict__ g, const unsigned short* __restrict__ gbf,
    const int* __restrict__ row_ptr, const int* __restrict__ esrc,
    const float* __restrict__ eps, const float* __restrict__ bl, float* __restrict__ out) {
    int gtid = blockIdx.x * 256 + threadIdx.x;
    int node = gtid >> 6;
    if (node >= N_NODES) return;
    int lane = threadIdx.x & 63;
    node = __builtin_amdgcn_readfirstlane(node);
    int beg = __builtin_amdgcn_readfirstlane(row_ptr[node]);
    int end = __builtin_amdgcn_readfirstlane(row_ptr[node + 1]);
    int half = lane >> 5;
    int fp = lane & 31;  // feat pair: feats 2fp, 2fp+1
    const unsigned short* gl = gbf + fp * 2;
    float ax = 0.f, ay = 0.f, bx = 0.f, by = 0.f;
    int e = beg + half;
    for (; e + 2 < end; e += 4) {
        int s0 = esrc[e], s1 = esrc[e + 2];
        unsigned v0 = *(const unsigned*)(gl + (size_t)s0 * 64);
        unsigned v1 = *(const unsigned*)(gl + (size_t)s1 * 64);
        ax += bf2f((unsigned short)v0); ay += bf2f((unsigned short)(v0 >> 16));
        bx += bf2f((unsigned short)v1); by += bf2f((unsigned short)(v1 >> 16));
    }
    for (; e < end; e += 2) {
        int s = esrc[e];
        unsigned v = *(const unsigned*)(gl + (size_t)s * 64);
        ax += bf2f((unsigned short)v);
        ay += bf2f((unsigned short)(v >> 16));
    }
    ax += bx;
    ay += by;
    ax += __shfl_xor(ax, 32);
    ay += __shfl_xor(ay, 32);
    if (half == 0) {
        int d = end - beg;
        float inv = (d > 0) ? 1.0f / (float)d : 0.0f;
        float ep = 1.0f + eps[3];
        float2 gv = *(const float2*)(g + (size_t)node * 64 + fp * 2);
        float2 r;
        r.x = ep * gv.x + ax * inv + bl[fp * 2];
        r.y = ep * gv.y + ay * inv + bl[fp * 2 + 1];
        *(float2*)(out + (size_t)node * 64 + fp * 2) = r;
    }
}

// ---------------- launch ----------------

extern "C" void kernel_launch(void* const* d_in, const int* in_sizes, int n_in,
                              void* d_out, int out_size, void* d_ws, size_t ws_size,
                              hipStream_t stream) {
    const float* X   = (const float*)d_in[0];
    const float* fcW = (const float*)d_in[1];
    const float* fcb = (const float*)d_in[2];
    const float* W   = (const float*)d_in[3];
    const float* b   = (const float*)d_in[4];
    const float* Wl  = (const float*)d_in[5];
    const float* bl  = (const float*)d_in[6];
    const float* eps = (const float*)d_in[7];
    const int* src   = (const int*)d_in[8];
    const int* dst   = (const int*)d_in[9];
    float* out = (float*)d_out;

    // workspace carve (~58 MB; was ~74 MB — u eliminated, bf16 payload ping-pongs)
    float* h = (float*)d_ws;                                    // 50000*128 f32, IN-PLACE across layers
    unsigned short* bfA = (unsigned short*)(h + (size_t)N_NODES * 128);  // 12.8MB payload ping
    unsigned short* bfB = bfA + (size_t)N_NODES * 128;                   // 12.8MB payload pong
    unsigned short* whi = bfB + (size_t)N_NODES * 128;          // 73728 bf16
    unsigned short* wlo = whi + 73728;                          // 73728 bf16
    int* bcnt    = (int*)(wlo + 73728);                         // NBUCK
    int* boff    = bcnt + NBUCK;                                // NBUCK+1
    int* cursor  = boff + NBUCK + 1;                            // NBUCK
    int* row_ptr = cursor + NBUCK;                              // N_NODES+1
    int* packed  = row_ptr + N_NODES + 1;                       // N_EDGES
    int* esrc    = packed + N_EDGES;                            // N_EDGES
    // last-layer overlays (dead buffers by the time they're written):
    float* g = (float*)bfB;            // 50000*64 f32 = 12.8MB, bfB dead after layer-1 gathers
    unsigned short* gbf = bfA;         // 50000*64 bf16 = 6.4MB, bfA dead after layer-2 gathers

    const int gemm_blocks = (N_NODES + 63) / 64;          // 782
    const int agg64_blocks = (N_NODES * 64 + 255) / 256;  // 12500
    const int prep_blocks = (73728 + 255) / 256;          // 288

    hipMemsetAsync(bcnt, 0, NBUCK * sizeof(int), stream);
    fused_hist_prep<<<NSTRIPE + prep_blocks, 256, 0, stream>>>(dst, bcnt, fcW, W, Wl, whi, wlo);
    bucket_scan<<<1, 256, 0, stream>>>(bcnt, boff, cursor, row_ptr);
    fused_binA_gemm<<<NSTRIPE + gemm_blocks, 256, 0, stream>>>(src, dst, cursor, packed, X, whi,
                                                               wlo, fcb, h, bfA);
    binB_kernel<<<NBUCK, 256, 0, stream>>>(packed, boff, row_ptr, esrc);

    // 3 hidden GIN layers, each one fused agg+GEMM dispatch (h updated in place,
    // bf16 gather payload ping-pongs A->B->A; layer 2's payload is never needed)
    fused_agg_gemm<true><<<gemm_blocks, 256, 0, stream>>>(h, bfA, row_ptr, esrc, eps, 0,
                                                          whi + 16384, wlo + 16384, b, bfB);
    fused_agg_gemm<true><<<gemm_blocks, 256, 0, stream>>>(h, bfB, row_ptr, esrc, eps, 1,
                                                          whi + 32768, wlo + 32768, b + 128, bfA);
    fused_agg_gemm<false><<<gemm_blocks, 256, 0, stream>>>(h, bfA, row_ptr, esrc, eps, 2,
                                                           whi + 49152, wlo + 49152, b + 256, bfB);

    // last layer, commuted: g = h @ Wl^T (no bias), then out = (1+eps3)*g + mean(g) + bl
    gemm_mfma<64, false, true, false><<<gemm_blocks, 256, 0, stream>>>(h, whi + 65536,
                                                                       wlo + 65536, nullptr, g,
                                                                       gbf, N_NODES);
    agg64_out<<<agg64_blocks, 256, 0, stream>>>(g, gbf, row_ptr, esrc, eps, bl, out);
}

// Round 2
// 421.159 us; speedup vs baseline: 1.0835x; 1.0835x over previous
//
#include <hip/hip_runtime.h>

#define N_NODES 50000
#define N_EDGES 800000
#define NBUCK 196                   // buckets of 256 nodes: bucket = dst >> 8
#define EPB 4096                    // edges per stripe-block in pass A
#define NSTRIPE ((N_EDGES + EPB - 1) / EPB)  // 196

typedef __attribute__((ext_vector_type(8))) short short8;
typedef __attribute__((ext_vector_type(4))) float float4v;

__device__ inline unsigned short f2bf(float f) {
    unsigned u = __float_as_uint(f);
    unsigned r = u + 0x7fff + ((u >> 16) & 1);
    return (unsigned short)(r >> 16);
}
__device__ inline float bf2f(unsigned short h) {
    return __uint_as_float(((unsigned)h) << 16);
}

// ---------------- fused: bucket histogram (196 blocks) + weight split (288) ----------

__global__ void __launch_bounds__(256) fused_hist_prep(
    const int* __restrict__ dst, int* __restrict__ bcnt, const float* __restrict__ fcW,
    const float* __restrict__ W, const float* __restrict__ Wl, unsigned short* __restrict__ hi,
    unsigned short* __restrict__ lo) {
    int bx = blockIdx.x;
    if (bx < NSTRIPE) {
        __shared__ int lhist[256];
        int t = threadIdx.x;
        lhist[t] = 0;
        __syncthreads();
        int base = bx * EPB + t;
#pragma unroll 4
        for (int k = 0; k < EPB / 256; k++) {
            int i = base + k * 256;
            if (i < N_EDGES) atomicAdd(&lhist[((unsigned)dst[i]) >> 8], 1);
        }
        __syncthreads();
        if (t < NBUCK) atomicAdd(&bcnt[t], lhist[t]);
    } else {
        // weight split: [0,16384) fcW | [16384,65536) W | [65536,73728) W_last
        int i = (bx - NSTRIPE) * 256 + threadIdx.x;
        float v;
        if (i < 16384) v = fcW[i];
        else if (i < 65536) v = W[i - 16384];
        else if (i < 73728) v = Wl[i - 65536];
        else return;
        unsigned short h = f2bf(v);
        hi[i] = h;
        lo[i] = f2bf(v - bf2f(h));
    }
}

// ---------------- bucket offsets (1 block) ----------------

__global__ void bucket_scan(const int* __restrict__ bcnt, int* __restrict__ boff,
                            int* __restrict__ cursor, int* __restrict__ row_ptr) {
    __shared__ int sm[256];
    int t = threadIdx.x;
    int v = (t < NBUCK) ? bcnt[t] : 0;
    sm[t] = v;
    __syncthreads();
    for (int o = 1; o < 256; o <<= 1) {
        int x = sm[t];
        int a = (t >= o) ? sm[t - o] : 0;
        __syncthreads();
        sm[t] = x + a;
        __syncthreads();
    }
    if (t < NBUCK) {
        boff[t] = sm[t] - v;
        cursor[t] = sm[t] - v;
    }
    if (t == NBUCK - 1) {
        boff[NBUCK] = sm[t];
        row_ptr[N_NODES] = sm[t];
    }
}

// ---------------- split-bf16 MFMA GEMM body ----------------
// D = Ahi*Whi + Alo*Whi + Ahi*Wlo (missing Alo*Wlo ~ 2^-18 rel).
// ASPLIT: A comes pre-split as bf16 hi/lo planes (agg emitted it); else fp32 + convert.

template <int COLS, bool RELU, bool WRITE_BF, bool BIAS, bool ASPLIT>
__device__ __forceinline__ void gemm_body(int bx, const float* __restrict__ U,
                                          const unsigned short* __restrict__ Uhi,
                                          const unsigned short* __restrict__ Ulo,
                                          const unsigned short* __restrict__ Whi,
                                          const unsigned short* __restrict__ Wlo,
                                          const float* __restrict__ bias, float* __restrict__ out,
                                          unsigned short* __restrict__ outbf, int nrows) {
    int wave = threadIdx.x >> 6;
    int lane = threadIdx.x & 63;
    int m = lane & 15;
    int quad = lane >> 4;
    int r0 = bx * 64 + wave * 16;
    int rowA = r0 + m;
    if (rowA >= nrows) rowA = nrows - 1;  // clamp OOB loads (stores guarded)

    short8 ahi[4], alo[4];
    if (ASPLIT) {
        const unsigned short* hp = Uhi + (size_t)rowA * 128 + quad * 8;
        const unsigned short* lp = Ulo + (size_t)rowA * 128 + quad * 8;
#pragma unroll
        for (int kc = 0; kc < 4; kc++) {
            ahi[kc] = *(const short8*)(hp + kc * 32);
            alo[kc] = *(const short8*)(lp + kc * 32);
        }
    } else {
        const float* arow = U + (size_t)rowA * 128 + quad * 8;
#pragma unroll
        for (int kc = 0; kc < 4; kc++) {
            float4 f0 = *(const float4*)(arow + kc * 32);
            float4 f1 = *(const float4*)(arow + kc * 32 + 4);
            float fv[8] = {f0.x, f0.y, f0.z, f0.w, f1.x, f1.y, f1.z, f1.w};
#pragma unroll
            for (int j = 0; j < 8; j++) {
                unsigned short h = f2bf(fv[j]);
                ahi[kc][j] = (short)h;
                alo[kc][j] = (short)f2bf(fv[j] - bf2f(h));
            }
        }
    }

#pragma unroll
    for (int nt = 0; nt < COLS / 16; nt++) {
        int n = nt * 16 + m;
        const unsigned short* bhp = Whi + (size_t)n * 128 + quad * 8;
        const unsigned short* blp = Wlo + (size_t)n * 128 + quad * 8;
        float4v acc = {0.f, 0.f, 0.f, 0.f};
#pragma unroll
        for (int kc = 0; kc < 4; kc++) {
            short8 bh = *(const short8*)(bhp + kc * 32);
            short8 bl = *(const short8*)(blp + kc * 32);
            acc = __builtin_amdgcn_mfma_f32_16x16x32_bf16(ahi[kc], bh, acc, 0, 0, 0);
            acc = __builtin_amdgcn_mfma_f32_16x16x32_bf16(alo[kc], bh, acc, 0, 0, 0);
            acc = __builtin_amdgcn_mfma_f32_16x16x32_bf16(ahi[kc], bl, acc, 0, 0, 0);
        }
        float bv = 0.f;
        if (BIAS) bv = bias[n];
#pragma unroll
        for (int i = 0; i < 4; i++) {
            int r = r0 + quad * 4 + i;
            if (r < nrows) {
                float v = acc[i] + bv;
                if (RELU) v = fmaxf(v, 0.f);
                out[(size_t)r * COLS + n] = v;
                if (WRITE_BF) outbf[(size_t)r * COLS + n] = f2bf(v);
            }
        }
    }
}

template <int COLS, bool RELU, bool WRITE_BF, bool BIAS, bool ASPLIT>
__global__ void __launch_bounds__(256) gemm_mfma(const float* __restrict__ U,
                                                 const unsigned short* __restrict__ Uhi,
                                                 const unsigned short* __restrict__ Ulo,
                                                 const unsigned short* __restrict__ Whi,
                                                 const unsigned short* __restrict__ Wlo,
                                                 const float* __restrict__ bias,
                                                 float* __restrict__ out,
                                                 unsigned short* __restrict__ outbf, int nrows) {
    gemm_body<COLS, RELU, WRITE_BF, BIAS, ASPLIT>(blockIdx.x, U, Uhi, Ulo, Whi, Wlo, bias, out,
                                                  outbf, nrows);
}

// ---------------- fused: pass A binning (196 blocks) + SLP GEMM (782) ----------

__global__ void __launch_bounds__(256) fused_binA_gemm(
    const int* __restrict__ src, const int* __restrict__ dst, int* __restrict__ cursor,
    int* __restrict__ packed, const float* __restrict__ X, const unsigned short* __restrict__ whi,
    const unsigned short* __restrict__ wlo, const float* __restrict__ fcb, float* __restrict__ h,
    unsigned short* __restrict__ hbf) {
    int bx = blockIdx.x;
    if (bx < NSTRIPE) {
        __shared__ int lcount[256];
        __shared__ int lbase[256];
        int t = threadIdx.x;
        lcount[t] = 0;
        __syncthreads();
        int base = bx * EPB + t;
#pragma unroll 4
        for (int k = 0; k < EPB / 256; k++) {
            int i = base + k * 256;
            if (i < N_EDGES) atomicAdd(&lcount[((unsigned)dst[i]) >> 8], 1);
        }
        __syncthreads();
        if (t < NBUCK) {
            lbase[t] = atomicAdd(&cursor[t], lcount[t]);
            lcount[t] = 0;
        }
        __syncthreads();
#pragma unroll 4
        for (int k = 0; k < EPB / 256; k++) {
            int i = base + k * 256;
            if (i < N_EDGES) {
                int d = dst[i];
                int wb = ((unsigned)d) >> 8;
                int p = lbase[wb] + atomicAdd(&lcount[wb], 1);
                packed[p] = ((d & 255) << 16) | src[i];
            }
        }
    } else {
        gemm_body<128, true, true, true, false>(bx - NSTRIPE, X, nullptr, nullptr, whi, wlo, fcb,
                                                h, hbf, N_NODES);
    }
}

// ---------------- pass B: per-bucket counting sort -> row_ptr + esrc ----------

__global__ void __launch_bounds__(256) binB_kernel(const int* __restrict__ packed,
                                                   const int* __restrict__ boff,
                                                   int* __restrict__ row_ptr,
                                                   int* __restrict__ esrc) {
    __shared__ int sm[256];
    __shared__ int curs[256];
    int b = blockIdx.x;
    int t = threadIdx.x;
    int e0 = boff[b], e1 = boff[b + 1];
    curs[t] = 0;  // use as histogram first
    __syncthreads();
    for (int i = e0 + t; i < e1; i += 256) atomicAdd(&curs[((unsigned)packed[i]) >> 16], 1);
    __syncthreads();
    int v = curs[t];
    sm[t] = v;
    __syncthreads();
    for (int o = 1; o < 256; o <<= 1) {
        int x = sm[t];
        int a = (t >= o) ? sm[t - o] : 0;
        __syncthreads();
        sm[t] = x + a;
        __syncthreads();
    }
    int excl = sm[t] - v;
    curs[t] = excl;
    int node = b * 256 + t;
    if (node < N_NODES) row_ptr[node] = e0 + excl;
    __syncthreads();
    for (int i = e0 + t; i < e1; i += 256) {
        unsigned w = (unsigned)packed[i];
        int p = atomicAdd(&curs[w >> 16], 1);
        esrc[e0 + p] = (int)(w & 0xFFFFu);
    }
}

// ---------------- Aggregation: u = (1+eps)*h + mean_{in}(h) ----------------
// One wave per node (12500 blocks -> max TLP for the latency-bound gather).
// bf16 gather payload (256 B/row), fp32 accumulate + fp32 self term.
// Emits u pre-split as bf16 hi/lo planes so the GEMM skips the f2bf work.

__global__ void __launch_bounds__(256) agg_kernel(
    const float* __restrict__ h, const unsigned short* __restrict__ hbf,
    const int* __restrict__ row_ptr, const int* __restrict__ esrc,
    const float* __restrict__ eps, int layer, unsigned* __restrict__ uhi32,
    unsigned* __restrict__ ulo32) {
    int gtid = blockIdx.x * 256 + threadIdx.x;
    int node = gtid >> 6;
    int lane = threadIdx.x & 63;
    if (node >= N_NODES) return;
    node = __builtin_amdgcn_readfirstlane(node);
    int beg = __builtin_amdgcn_readfirstlane(row_ptr[node]);
    int end = __builtin_amdgcn_readfirstlane(row_ptr[node + 1]);

    const unsigned short* hl = hbf + lane * 2;
    float a0x = 0.f, a0y = 0.f, a1x = 0.f, a1y = 0.f;
    float a2x = 0.f, a2y = 0.f, a3x = 0.f, a3y = 0.f;
    int e = beg;
    for (; e + 3 < end; e += 4) {
        int s0 = esrc[e], s1 = esrc[e + 1], s2 = esrc[e + 2], s3 = esrc[e + 3];
        unsigned v0 = *(const unsigned*)(hl + (size_t)s0 * 128);
        unsigned v1 = *(const unsigned*)(hl + (size_t)s1 * 128);
        unsigned v2 = *(const unsigned*)(hl + (size_t)s2 * 128);
        unsigned v3 = *(const unsigned*)(hl + (size_t)s3 * 128);
        a0x += bf2f((unsigned short)v0); a0y += bf2f((unsigned short)(v0 >> 16));
        a1x += bf2f((unsigned short)v1); a1y += bf2f((unsigned short)(v1 >> 16));
        a2x += bf2f((unsigned short)v2); a2y += bf2f((unsigned short)(v2 >> 16));
        a3x += bf2f((unsigned short)v3); a3y += bf2f((unsigned short)(v3 >> 16));
    }
    for (; e < end; e++) {
        int s = esrc[e];
        unsigned v = *(const unsigned*)(hl + (size_t)s * 128);
        a0x += bf2f((unsigned short)v);
        a0y += bf2f((unsigned short)(v >> 16));
    }
    float sx = (a0x + a1x) + (a2x + a3x);
    float sy = (a0y + a1y) + (a2y + a3y);
    int d = end - beg;
    float inv = (d > 0) ? 1.0f / (float)d : 0.0f;
    float ep = 1.0f + eps[layer];
    float2 hv = *(const float2*)(h + (size_t)node * 128 + lane * 2);
    float ux = ep * hv.x + sx * inv;
    float uy = ep * hv.y + sy * inv;
    unsigned short u0 = f2bf(ux), u1 = f2bf(uy);
    size_t o = (size_t)node * 64 + lane;
    uhi32[o] = (unsigned)u0 | ((unsigned)u1 << 16);
    ulo32[o] = (unsigned)f2bf(ux - bf2f(u0)) | ((unsigned)f2bf(uy - bf2f(u1)) << 16);
}

// ---------------- last layer, commuted: out = (1+eps3)*g + mean(g) + b ----------------
// g = h @ Wl^T (64-wide) -> gather volume halved vs aggregating 128-wide h.
// One wave per node; half-wave per edge, dword bf16-pair gathers, shfl_xor(32) combine.

__global__ void __launch_bounds__(256) agg64_out(
    const float* __restrict__ g, const unsigned short* __restrict__ gbf,
    const int* __restrict__ row_ptr, const int* __restrict__ esrc,
    const float* __restrict__ eps, const float* __restrict__ bl, float* __restrict__ out) {
    int gtid = blockIdx.x * 256 + threadIdx.x;
    int node = gtid >> 6;
    if (node >= N_NODES) return;
    int lane = threadIdx.x & 63;
    node = __builtin_amdgcn_readfirstlane(node);
    int beg = __builtin_amdgcn_readfirstlane(row_ptr[node]);
    int end = __builtin_amdgcn_readfirstlane(row_ptr[node + 1]);
    int half = lane >> 5;
    int fp = lane & 31;  // feat pair: feats 2fp, 2fp+1
    const unsigned short* gl = gbf + fp * 2;
    float ax = 0.f, ay = 0.f, bx = 0.f, by = 0.f;
    int e = beg + half;
    for (; e + 2 < end; e += 4) {
        int s0 = esrc[e], s1 = esrc[e + 2];
        unsigned v0 = *(const unsigned*)(gl + (size_t)s0 * 64);
        unsigned v1 = *(const unsigned*)(gl + (size_t)s1 * 64);
        ax += bf2f((unsigned short)v0); ay += bf2f((unsigned short)(v0 >> 16));
        bx += bf2f((unsigned short)v1); by += bf2f((unsigned short)(v1 >> 16));
    }
    for (; e < end; e += 2) {
        int s = esrc[e];
        unsigned v = *(const unsigned*)(gl + (size_t)s * 64);
        ax += bf2f((unsigned short)v);
        ay += bf2f((unsigned short)(v >> 16));
    }
    ax += bx;
    ay += by;
    ax += __shfl_xor(ax, 32);
    ay += __shfl_xor(ay, 32);
    if (half == 0) {
        int d = end - beg;
        float inv = (d > 0) ? 1.0f / (float)d : 0.0f;
        float ep = 1.0f + eps[3];
        float2 gv = *(const float2*)(g + (size_t)node * 64 + fp * 2);
        float2 r;
        r.x = ep * gv.x + ax * inv + bl[fp * 2];
        r.y = ep * gv.y + ay * inv + bl[fp * 2 + 1];
        *(float2*)(out + (size_t)node * 64 + fp * 2) = r;
    }
}

// ---------------- launch ----------------

extern "C" void kernel_launch(void* const* d_in, const int* in_sizes, int n_in,
                              void* d_out, int out_size, void* d_ws, size_t ws_size,
                              hipStream_t stream) {
    const float* X   = (const float*)d_in[0];
    const float* fcW = (const float*)d_in[1];
    const float* fcb = (const float*)d_in[2];
    const float* W   = (const float*)d_in[3];
    const float* b   = (const float*)d_in[4];
    const float* Wl  = (const float*)d_in[5];
    const float* bl  = (const float*)d_in[6];
    const float* eps = (const float*)d_in[7];
    const int* src   = (const int*)d_in[8];
    const int* dst   = (const int*)d_in[9];
    float* out = (float*)d_out;

    // workspace carve (~62 MB)
    float* h = (float*)d_ws;                                    // 50000*128 f32
    unsigned short* hbf = (unsigned short*)(h + (size_t)N_NODES * 128);  // 12.8MB bf16 payload
    unsigned short* uhi = hbf + (size_t)N_NODES * 128;          // 12.8MB split-bf16 u (hi)
    unsigned short* ulo = uhi + (size_t)N_NODES * 128;          // 12.8MB split-bf16 u (lo)
    unsigned short* whi = ulo + (size_t)N_NODES * 128;          // 73728 bf16
    unsigned short* wlo = whi + 73728;                          // 73728 bf16
    int* bcnt    = (int*)(wlo + 73728);                         // NBUCK
    int* boff    = bcnt + NBUCK;                                // NBUCK+1
    int* cursor  = boff + NBUCK + 1;                            // NBUCK
    int* row_ptr = cursor + NBUCK;                              // N_NODES+1
    int* packed  = row_ptr + N_NODES + 1;                       // N_EDGES
    int* esrc    = packed + N_EDGES;                            // N_EDGES
    // last-layer overlays (uhi/ulo dead after layer-3 GEMM consumed them):
    float* g = (float*)uhi;            // 50000*64 f32 = 12.8MB
    unsigned short* gbf = ulo;         // 50000*64 bf16 = 6.4MB

    const int gemm_blocks = (N_NODES + 63) / 64;          // 782
    const int agg_blocks = (N_NODES * 64 + 255) / 256;    // 12500
    const int prep_blocks = (73728 + 255) / 256;          // 288

    hipMemsetAsync(bcnt, 0, NBUCK * sizeof(int), stream);
    fused_hist_prep<<<NSTRIPE + prep_blocks, 256, 0, stream>>>(dst, bcnt, fcW, W, Wl, whi, wlo);
    bucket_scan<<<1, 256, 0, stream>>>(bcnt, boff, cursor, row_ptr);
    fused_binA_gemm<<<NSTRIPE + gemm_blocks, 256, 0, stream>>>(src, dst, cursor, packed, X, whi,
                                                               wlo, fcb, h, hbf);
    binB_kernel<<<NBUCK, 256, 0, stream>>>(packed, boff, row_ptr, esrc);

    // 3 hidden GIN layers: max-TLP agg (emits split-bf16 u) + MFMA GEMM
    for (int i = 0; i < 3; i++) {
        agg_kernel<<<agg_blocks, 256, 0, stream>>>(h, hbf, row_ptr, esrc, eps, i,
                                                   (unsigned*)uhi, (unsigned*)ulo);
        if (i < 2)
            gemm_mfma<128, true, true, true, true><<<gemm_blocks, 256, 0, stream>>>(
                nullptr, uhi, ulo, whi + 16384 + (size_t)i * 16384,
                wlo + 16384 + (size_t)i * 16384, b + (size_t)i * 128, h, hbf, N_NODES);
        else
            gemm_mfma<128, true, false, true, true><<<gemm_blocks, 256, 0, stream>>>(
                nullptr, uhi, ulo, whi + 16384 + (size_t)i * 16384,
                wlo + 16384 + (size_t)i * 16384, b + (size_t)i * 128, h, nullptr, N_NODES);
    }

    // last layer, commuted: g = h @ Wl^T (no bias), then out = (1+eps3)*g + mean(g) + bl
    gemm_mfma<64, false, true, false, false><<<gemm_blocks, 256, 0, stream>>>(
        h, nullptr, nullptr, whi + 65536, wlo + 65536, nullptr, g, gbf, N_NODES);
    agg64_out<<<agg_blocks, 256, 0, stream>>>(g, gbf, row_ptr, esrc, eps, bl, out);
}

// Round 3
// 403.816 us; speedup vs baseline: 1.1301x; 1.0429x over previous
//
#include <hip/hip_runtime.h>

#define N_NODES 50000
#define N_EDGES 800000
#define NBUCK 196                   // buckets of 256 nodes: bucket = dst >> 8
#define CAP 4608                    // fixed bucket capacity (mean 4082, sigma ~64 -> 8 sigma)
#define EPB 4096                    // edges per stripe-block in pass A
#define NSTRIPE ((N_EDGES + EPB - 1) / EPB)  // 196

typedef __attribute__((ext_vector_type(8))) short short8;
typedef __attribute__((ext_vector_type(4))) float float4v;

__device__ inline unsigned short f2bf(float f) {
    unsigned u = __float_as_uint(f);
    unsigned r = u + 0x7fff + ((u >> 16) & 1);
    return (unsigned short)(r >> 16);
}
__device__ inline float bf2f(unsigned short h) {
    return __uint_as_float(((unsigned)h) << 16);
}

// ---------------- weight split (288 blocks) + cursor init ----------------

__global__ void __launch_bounds__(256) wsplit_init(
    const float* __restrict__ fcW, const float* __restrict__ W, const float* __restrict__ Wl,
    unsigned short* __restrict__ hi, unsigned short* __restrict__ lo, int* __restrict__ cursor) {
    if (blockIdx.x == 0 && threadIdx.x < NBUCK) cursor[threadIdx.x] = threadIdx.x * CAP;
    int i = blockIdx.x * 256 + threadIdx.x;
    float v;
    if (i < 16384) v = fcW[i];
    else if (i < 65536) v = W[i - 16384];
    else if (i < 73728) v = Wl[i - 65536];
    else return;
    unsigned short h = f2bf(v);
    hi[i] = h;
    lo[i] = f2bf(v - bf2f(h));
}

// ---------------- bucket offsets from observed counts (1 block, after binA) --------

__global__ void bucket_scan(const int* __restrict__ cursor, int* __restrict__ boff,
                            int* __restrict__ row_ptr) {
    __shared__ int sm[256];
    int t = threadIdx.x;
    int v = (t < NBUCK) ? (cursor[t] - t * CAP) : 0;
    sm[t] = v;
    __syncthreads();
    for (int o = 1; o < 256; o <<= 1) {
        int x = sm[t];
        int a = (t >= o) ? sm[t - o] : 0;
        __syncthreads();
        sm[t] = x + a;
        __syncthreads();
    }
    if (t < NBUCK) boff[t] = sm[t] - v;
    if (t == NBUCK - 1) {
        boff[NBUCK] = sm[t];
        row_ptr[N_NODES] = sm[t];
    }
}

// ---------------- split-bf16 MFMA GEMM body ----------------
// D = Ahi*Whi + Alo*Whi + Ahi*Wlo (missing Alo*Wlo ~ 2^-18 rel).
// ASPLIT: A comes pre-split as bf16 hi/lo planes (agg emitted it); else fp32 + convert.

template <int COLS, bool RELU, bool WRITE_BF, bool BIAS, bool ASPLIT>
__device__ __forceinline__ void gemm_body(int bx, const float* __restrict__ U,
                                          const unsigned short* __restrict__ Uhi,
                                          const unsigned short* __restrict__ Ulo,
                                          const unsigned short* __restrict__ Whi,
                                          const unsigned short* __restrict__ Wlo,
                                          const float* __restrict__ bias, float* __restrict__ out,
                                          unsigned short* __restrict__ outbf, int nrows) {
    int wave = threadIdx.x >> 6;
    int lane = threadIdx.x & 63;
    int m = lane & 15;
    int quad = lane >> 4;
    int r0 = bx * 64 + wave * 16;
    int rowA = r0 + m;
    if (rowA >= nrows) rowA = nrows - 1;  // clamp OOB loads (stores guarded)

    short8 ahi[4], alo[4];
    if (ASPLIT) {
        const unsigned short* hp = Uhi + (size_t)rowA * 128 + quad * 8;
        const unsigned short* lp = Ulo + (size_t)rowA * 128 + quad * 8;
#pragma unroll
        for (int kc = 0; kc < 4; kc++) {
            ahi[kc] = *(const short8*)(hp + kc * 32);
            alo[kc] = *(const short8*)(lp + kc * 32);
        }
    } else {
        const float* arow = U + (size_t)rowA * 128 + quad * 8;
#pragma unroll
        for (int kc = 0; kc < 4; kc++) {
            float4 f0 = *(const float4*)(arow + kc * 32);
            float4 f1 = *(const float4*)(arow + kc * 32 + 4);
            float fv[8] = {f0.x, f0.y, f0.z, f0.w, f1.x, f1.y, f1.z, f1.w};
#pragma unroll
            for (int j = 0; j < 8; j++) {
                unsigned short h = f2bf(fv[j]);
                ahi[kc][j] = (short)h;
                alo[kc][j] = (short)f2bf(fv[j] - bf2f(h));
            }
        }
    }

#pragma unroll
    for (int nt = 0; nt < COLS / 16; nt++) {
        int n = nt * 16 + m;
        const unsigned short* bhp = Whi + (size_t)n * 128 + quad * 8;
        const unsigned short* blp = Wlo + (size_t)n * 128 + quad * 8;
        float4v acc = {0.f, 0.f, 0.f, 0.f};
#pragma unroll
        for (int kc = 0; kc < 4; kc++) {
            short8 bh = *(const short8*)(bhp + kc * 32);
            short8 bl = *(const short8*)(blp + kc * 32);
            acc = __builtin_amdgcn_mfma_f32_16x16x32_bf16(ahi[kc], bh, acc, 0, 0, 0);
            acc = __builtin_amdgcn_mfma_f32_16x16x32_bf16(alo[kc], bh, acc, 0, 0, 0);
            acc = __builtin_amdgcn_mfma_f32_16x16x32_bf16(ahi[kc], bl, acc, 0, 0, 0);
        }
        float bv = 0.f;
        if (BIAS) bv = bias[n];
#pragma unroll
        for (int i = 0; i < 4; i++) {
            int r = r0 + quad * 4 + i;
            if (r < nrows) {
                float v = acc[i] + bv;
                if (RELU) v = fmaxf(v, 0.f);
                out[(size_t)r * COLS + n] = v;
                if (WRITE_BF) outbf[(size_t)r * COLS + n] = f2bf(v);
            }
        }
    }
}

template <int COLS, bool RELU, bool WRITE_BF, bool BIAS, bool ASPLIT>
__global__ void __launch_bounds__(256) gemm_mfma(const float* __restrict__ U,
                                                 const unsigned short* __restrict__ Uhi,
                                                 const unsigned short* __restrict__ Ulo,
                                                 const unsigned short* __restrict__ Whi,
                                                 const unsigned short* __restrict__ Wlo,
                                                 const float* __restrict__ bias,
                                                 float* __restrict__ out,
                                                 unsigned short* __restrict__ outbf, int nrows) {
    gemm_body<COLS, RELU, WRITE_BF, BIAS, ASPLIT>(blockIdx.x, U, Uhi, Ulo, Whi, Wlo, bias, out,
                                                  outbf, nrows);
}

// ---------------- fused: pass A binning (196 blocks) + SLP GEMM (782) ----------
// Binning reserves dense runs directly in per-bucket fixed-capacity regions
// (cursor[b] starts at b*CAP) -- no histogram pre-pass needed.

__global__ void __launch_bounds__(256) fused_binA_gemm(
    const int* __restrict__ src, const int* __restrict__ dst, int* __restrict__ cursor,
    int* __restrict__ packed, const float* __restrict__ X, const unsigned short* __restrict__ whi,
    const unsigned short* __restrict__ wlo, const float* __restrict__ fcb, float* __restrict__ h,
    unsigned short* __restrict__ hbf) {
    int bx = blockIdx.x;
    if (bx < NSTRIPE) {
        __shared__ int lcount[256];
        __shared__ int lbase[256];
        int t = threadIdx.x;
        lcount[t] = 0;
        __syncthreads();
        int base = bx * EPB + t;
#pragma unroll 4
        for (int k = 0; k < EPB / 256; k++) {
            int i = base + k * 256;
            if (i < N_EDGES) atomicAdd(&lcount[((unsigned)dst[i]) >> 8], 1);
        }
        __syncthreads();
        if (t < NBUCK) {
            lbase[t] = atomicAdd(&cursor[t], lcount[t]);
            lcount[t] = 0;
        }
        __syncthreads();
#pragma unroll 4
        for (int k = 0; k < EPB / 256; k++) {
            int i = base + k * 256;
            if (i < N_EDGES) {
                int d = dst[i];
                int wb = ((unsigned)d) >> 8;
                int p = lbase[wb] + atomicAdd(&lcount[wb], 1);
                if (p < (wb + 1) * CAP)  // overflow guard (never expected at 8 sigma)
                    packed[p] = ((d & 255) << 16) | src[i];
            }
        }
    } else {
        gemm_body<128, true, true, true, false>(bx - NSTRIPE, X, nullptr, nullptr, whi, wlo, fcb,
                                                h, hbf, N_NODES);
    }
}

// ---------------- pass B: per-bucket counting sort -> row_ptr + esrc ----------
// Reads sparse region [b*CAP, cursor[b]), writes dense esrc at boff[b].

__global__ void __launch_bounds__(256) binB_kernel(const int* __restrict__ packed,
                                                   const int* __restrict__ cursor,
                                                   const int* __restrict__ boff,
                                                   int* __restrict__ row_ptr,
                                                   int* __restrict__ esrc) {
    __shared__ int sm[256];
    __shared__ int curs[256];
    int b = blockIdx.x;
    int t = threadIdx.x;
    int e0r = b * CAP, e1r = cursor[b];
    int w0 = boff[b];
    curs[t] = 0;  // use as histogram first
    __syncthreads();
    for (int i = e0r + t; i < e1r; i += 256) atomicAdd(&curs[((unsigned)packed[i]) >> 16], 1);
    __syncthreads();
    int v = curs[t];
    sm[t] = v;
    __syncthreads();
    for (int o = 1; o < 256; o <<= 1) {
        int x = sm[t];
        int a = (t >= o) ? sm[t - o] : 0;
        __syncthreads();
        sm[t] = x + a;
        __syncthreads();
    }
    int excl = sm[t] - v;
    curs[t] = excl;
    int node = b * 256 + t;
    if (node < N_NODES) row_ptr[node] = w0 + excl;
    __syncthreads();
    for (int i = e0r + t; i < e1r; i += 256) {
        unsigned w = (unsigned)packed[i];
        int p = atomicAdd(&curs[w >> 16], 1);
        esrc[w0 + p] = (int)(w & 0xFFFFu);
    }
}

// ---------------- Aggregation: u = (1+eps)*h + mean_{in}(h) ----------------
// One wave per node. Wide gather: lane = (edge-slot eg = lane>>4, feat-quad fo = lane&15);
// each instruction loads 4 full 256B rows (64 lanes x 16B). Cross-edge-slot reduction
// deferred to 16 shfl_xor per NODE. Emits u pre-split as bf16 hi/lo planes.

__global__ void __launch_bounds__(256) agg_kernel(
    const float* __restrict__ h, const unsigned short* __restrict__ hbf,
    const int* __restrict__ row_ptr, const int* __restrict__ esrc,
    const float* __restrict__ eps, int layer, unsigned* __restrict__ uhi32,
    unsigned* __restrict__ ulo32) {
    int gtid = blockIdx.x * 256 + threadIdx.x;
    int node = gtid >> 6;
    int lane = threadIdx.x & 63;
    if (node >= N_NODES) return;
    node = __builtin_amdgcn_readfirstlane(node);
    int beg = __builtin_amdgcn_readfirstlane(row_ptr[node]);
    int end = __builtin_amdgcn_readfirstlane(row_ptr[node + 1]);
    int eg = lane >> 4;   // edge slot 0..3
    int fo = lane & 15;   // feat quad: feats fo*8 .. fo*8+7

    float acc[8] = {0.f, 0.f, 0.f, 0.f, 0.f, 0.f, 0.f, 0.f};
    int e = beg;
#pragma unroll 2
    for (; e + 3 < end; e += 4) {
        int s = esrc[e + eg];
        short8 v = *(const short8*)(hbf + (size_t)s * 128 + fo * 8);
#pragma unroll
        for (int j = 0; j < 8; j++) acc[j] += bf2f((unsigned short)v[j]);
    }
    int rem = end - e;
    if (eg < rem) {
        int s = esrc[e + eg];
        short8 v = *(const short8*)(hbf + (size_t)s * 128 + fo * 8);
#pragma unroll
        for (int j = 0; j < 8; j++) acc[j] += bf2f((unsigned short)v[j]);
    }
#pragma unroll
    for (int j = 0; j < 8; j++) {
        acc[j] += __shfl_xor(acc[j], 16);
        acc[j] += __shfl_xor(acc[j], 32);
    }
    if (eg == 0) {  // lanes 0..15 finalize + store (16 lanes x 16B = 256B per instr)
        int d = end - beg;
        float inv = (d > 0) ? 1.0f / (float)d : 0.0f;
        float ep = 1.0f + eps[layer];
        const float* hr = h + (size_t)node * 128 + fo * 8;
        float4 h0 = *(const float4*)hr;
        float4 h1 = *(const float4*)(hr + 4);
        float hv[8] = {h0.x, h0.y, h0.z, h0.w, h1.x, h1.y, h1.z, h1.w};
        unsigned hip[4], lop[4];
#pragma unroll
        for (int jj = 0; jj < 4; jj++) {
            float ux = ep * hv[2 * jj] + acc[2 * jj] * inv;
            float uy = ep * hv[2 * jj + 1] + acc[2 * jj + 1] * inv;
            unsigned short uh0 = f2bf(ux), uh1 = f2bf(uy);
            hip[jj] = (unsigned)uh0 | ((unsigned)uh1 << 16);
            lop[jj] = (unsigned)f2bf(ux - bf2f(uh0)) | ((unsigned)f2bf(uy - bf2f(uh1)) << 16);
        }
        uint4* ph = (uint4*)(uhi32 + (size_t)node * 64 + fo * 4);
        uint4* pl = (uint4*)(ulo32 + (size_t)node * 64 + fo * 4);
        *ph = make_uint4(hip[0], hip[1], hip[2], hip[3]);
        *pl = make_uint4(lop[0], lop[1], lop[2], lop[3]);
    }
}

// ---------------- last layer, commuted: out = (1+eps3)*g + mean(g) + b ----------------
// g = h @ Wl^T (64-wide). Wide gather: 8 edges per instruction (8 lanes x 16B per 128B row).

__global__ void __launch_bounds__(256) agg64_out(
    const float* __restrict__ g, const unsigned short* __restrict__ gbf,
    const int* __restrict__ row_ptr, const int* __restrict__ esrc,
    const float* __restrict__ eps, const float* __restrict__ bl, float* __restrict__ out) {
    int gtid = blockIdx.x * 256 + threadIdx.x;
    int node = gtid >> 6;
    if (node >= N_NODES) return;
    int lane = threadIdx.x & 63;
    node = __builtin_amdgcn_readfirstlane(node);
    int beg = __builtin_amdgcn_readfirstlane(row_ptr[node]);
    int end = __builtin_amdgcn_readfirstlane(row_ptr[node + 1]);
    int eg = lane >> 3;  // edge slot 0..7
    int fo = lane & 7;   // feat quad: feats fo*8 .. fo*8+7

    float acc[8] = {0.f, 0.f, 0.f, 0.f, 0.f, 0.f, 0.f, 0.f};
    int e = beg;
#pragma unroll 2
    for (; e + 7 < end; e += 8) {
        int s = esrc[e + eg];
        short8 v = *(const short8*)(gbf + (size_t)s * 64 + fo * 8);
#pragma unroll
        for (int j = 0; j < 8; j++) acc[j] += bf2f((unsigned short)v[j]);
    }
    int rem = end - e;
    if (eg < rem) {
        int s = esrc[e + eg];
        short8 v = *(const short8*)(gbf + (size_t)s * 64 + fo * 8);
#pragma unroll
        for (int j = 0; j < 8; j++) acc[j] += bf2f((unsigned short)v[j]);
    }
#pragma unroll
    for (int j = 0; j < 8; j++) {
        acc[j] += __shfl_xor(acc[j], 8);
        acc[j] += __shfl_xor(acc[j], 16);
        acc[j] += __shfl_xor(acc[j], 32);
    }
    if (eg == 0) {  // lanes 0..7 finalize + store
        int d = end - beg;
        float inv = (d > 0) ? 1.0f / (float)d : 0.0f;
        float ep = 1.0f + eps[3];
        const float* gr = g + (size_t)node * 64 + fo * 8;
        float4 g0 = *(const float4*)gr;
        float4 g1 = *(const float4*)(gr + 4);
        const float* blr = bl + fo * 8;
        float4 b0 = *(const float4*)blr;
        float4 b1 = *(const float4*)(blr + 4);
        float4 r0, r1;
        r0.x = ep * g0.x + acc[0] * inv + b0.x;
        r0.y = ep * g0.y + acc[1] * inv + b0.y;
        r0.z = ep * g0.z + acc[2] * inv + b0.z;
        r0.w = ep * g0.w + acc[3] * inv + b0.w;
        r1.x = ep * g1.x + acc[4] * inv + b1.x;
        r1.y = ep * g1.y + acc[5] * inv + b1.y;
        r1.z = ep * g1.z + acc[6] * inv + b1.z;
        r1.w = ep * g1.w + acc[7] * inv + b1.w;
        float* op = out + (size_t)node * 64 + fo * 8;
        *(float4*)op = r0;
        *(float4*)(op + 4) = r1;
    }
}

// ---------------- launch ----------------

extern "C" void kernel_launch(void* const* d_in, const int* in_sizes, int n_in,
                              void* d_out, int out_size, void* d_ws, size_t ws_size,
                              hipStream_t stream) {
    const float* X   = (const float*)d_in[0];
    const float* fcW = (const float*)d_in[1];
    const float* fcb = (const float*)d_in[2];
    const float* W   = (const float*)d_in[3];
    const float* b   = (const float*)d_in[4];
    const float* Wl  = (const float*)d_in[5];
    const float* bl  = (const float*)d_in[6];
    const float* eps = (const float*)d_in[7];
    const int* src   = (const int*)d_in[8];
    const int* dst   = (const int*)d_in[9];
    float* out = (float*)d_out;

    // workspace carve (~66 MB)
    float* h = (float*)d_ws;                                    // 50000*128 f32
    unsigned short* hbf = (unsigned short*)(h + (size_t)N_NODES * 128);  // 12.8MB bf16 payload
    unsigned short* uhi = hbf + (size_t)N_NODES * 128;          // 12.8MB split-bf16 u (hi)
    unsigned short* ulo = uhi + (size_t)N_NODES * 128;          // 12.8MB split-bf16 u (lo)
    unsigned short* whi = ulo + (size_t)N_NODES * 128;          // 73728 bf16
    unsigned short* wlo = whi + 73728;                          // 73728 bf16
    int* cursor  = (int*)(wlo + 73728);                         // NBUCK
    int* boff    = cursor + NBUCK;                              // NBUCK+1
    int* row_ptr = boff + NBUCK + 1;                            // N_NODES+1
    int* packed  = row_ptr + N_NODES + 1;                       // NBUCK*CAP sparse
    int* esrc    = packed + NBUCK * CAP;                        // N_EDGES
    // last-layer overlays (uhi/ulo dead after layer-3 GEMM consumed them):
    float* g = (float*)uhi;            // 50000*64 f32 = 12.8MB
    unsigned short* gbf = ulo;         // 50000*64 bf16 = 6.4MB

    const int gemm_blocks = (N_NODES + 63) / 64;          // 782
    const int agg_blocks = (N_NODES * 64 + 255) / 256;    // 12500
    const int prep_blocks = (73728 + 255) / 256;          // 288

    wsplit_init<<<prep_blocks, 256, 0, stream>>>(fcW, W, Wl, whi, wlo, cursor);
    fused_binA_gemm<<<NSTRIPE + gemm_blocks, 256, 0, stream>>>(src, dst, cursor, packed, X, whi,
                                                               wlo, fcb, h, hbf);
    bucket_scan<<<1, 256, 0, stream>>>(cursor, boff, row_ptr);
    binB_kernel<<<NBUCK, 256, 0, stream>>>(packed, cursor, boff, row_ptr, esrc);

    // 3 hidden GIN layers: wide-gather agg (emits split-bf16 u) + MFMA GEMM
    for (int i = 0; i < 3; i++) {
        agg_kernel<<<agg_blocks, 256, 0, stream>>>(h, hbf, row_ptr, esrc, eps, i,
                                                   (unsigned*)uhi, (unsigned*)ulo);
        if (i < 2)
            gemm_mfma<128, true, true, true, true><<<gemm_blocks, 256, 0, stream>>>(
                nullptr, uhi, ulo, whi + 16384 + (size_t)i * 16384,
                wlo + 16384 + (size_t)i * 16384, b + (size_t)i * 128, h, hbf, N_NODES);
        else
            gemm_mfma<128, true, false, true, true><<<gemm_blocks, 256, 0, stream>>>(
                nullptr, uhi, ulo, whi + 16384 + (size_t)i * 16384,
                wlo + 16384 + (size_t)i * 16384, b + (size_t)i * 128, h, nullptr, N_NODES);
    }

    // last layer, commuted: g = h @ Wl^T (no bias), then out = (1+eps3)*g + mean(g) + bl
    gemm_mfma<64, false, true, false, false><<<gemm_blocks, 256, 0, stream>>>(
        h, nullptr, nullptr, whi + 65536, wlo + 65536, nullptr, g, gbf, N_NODES);
    agg64_out<<<agg_blocks, 256, 0, stream>>>(g, gbf, row_ptr, esrc, eps, bl, out);
}